// Round 1
// baseline (332.526 us; speedup 1.0000x reference)
//
#include <hip/hip_runtime.h>
#include <hip/hip_fp16.h>
#include <cstdint>

#define DM    1472
#define NH    6
#define DKV   64
#define INNER 384
#define BATCH 4
#define SEQ   2048

typedef __attribute__((ext_vector_type(8))) _Float16 half8;
typedef __attribute__((ext_vector_type(4))) float f32x4;

__device__ __forceinline__ int swz64(int row, int b)  { return b ^ (((row >> 1) & 3) << 4); }
__device__ __forceinline__ int swz128(int row, int b) { return b ^ ((row & 7) << 4); }

// ---------------- prep: weights fp32 -> fp16 transposed ----------------
__global__ void prep_weights(const float* __restrict__ WQ, const float* __restrict__ WK,
                             const float* __restrict__ WV, const float* __restrict__ WO,
                             _Float16* __restrict__ WqT, _Float16* __restrict__ WkT,
                             _Float16* __restrict__ WvT, _Float16* __restrict__ WoT) {
  int idx = blockIdx.x * blockDim.x + threadIdx.x;
  const int per = DM * INNER;
  if (idx >= 4 * per) return;
  int which = idx / per;
  int i = idx - which * per;
  if (which < 3) {
    const float* W = which == 0 ? WQ : (which == 1 ? WK : WV);
    _Float16* T = which == 0 ? WqT : (which == 1 ? WkT : WvT);
    int k = i / INNER, n = i - (i / INNER) * INNER;
    T[(size_t)n * DM + k] = (_Float16)W[i];   // [INNER][DM] = W^T
  } else {
    int k = i / DM, n = i - (i / DM) * DM;
    WoT[(size_t)n * INNER + k] = (_Float16)WO[i];  // [DM][INNER] = WO^T
  }
}

// ---------------- prep: relative-position bias table [NH][4095] ----------------
// bucket thresholds derived exactly from the fp32 reference formula
__global__ void prep_bias(const float* __restrict__ rel_bias, float* __restrict__ biasT) {
  int idx = blockIdx.x * blockDim.x + threadIdx.x;
  if (idx >= NH * 4095) return;
  int h = idx / 4095;
  int j = idx - h * 4095;
  int d = j - 2047;                 // relative position k - q
  int ret = d > 0 ? 16 : 0;
  int a = d < 0 ? -d : d;
  int bucket;
  if (a < 8) bucket = ret + a;
  else {
    int large;
    if      (a >= 91) large = 15;
    else if (a >= 64) large = 14;
    else if (a >= 46) large = 13;
    else if (a >= 32) large = 12;
    else if (a >= 23) large = 11;
    else if (a >= 16) large = 10;
    else if (a >= 12) large = 9;
    else              large = 8;
    bucket = ret + large;
  }
  biasT[h * 4095 + j] = rel_bias[bucket * NH + h];
}

// ---------------- projection GEMM: X[8192,1472]fp32 @ W -> Q/K/V fp16 ----------------
// z=0: Q (from q_sequences), z=1: K, z=2: V^T (all from kv_sequences)
__global__ __launch_bounds__(256) void proj_gemm(
    const float* __restrict__ Xq, const float* __restrict__ Xkv,
    const _Float16* __restrict__ WqT, const _Float16* __restrict__ WkT, const _Float16* __restrict__ WvT,
    _Float16* __restrict__ Qo, _Float16* __restrict__ Ko, _Float16* __restrict__ Vto) {
  const int z = blockIdx.z;
  const float* __restrict__ X = (z == 0) ? Xq : Xkv;
  const _Float16* __restrict__ WT = (z == 0) ? WqT : (z == 1 ? WkT : WvT);

  __shared__ alignas(16) _Float16 As[128 * 32];
  __shared__ alignas(16) _Float16 Bs[64 * 32];
  char* AsB = (char*)As;
  char* BsB = (char*)Bs;

  const int tid = threadIdx.x;
  const int lane = tid & 63, wave = tid >> 6;
  const int wm = wave >> 1, wn = wave & 1;
  const int bm = blockIdx.x, bn = blockIdx.y;
  const int l15 = lane & 15, lg = lane >> 4;

  f32x4 acc[4][2] = {};

  const int arow = tid >> 1, aseg = tid & 1;    // A: 128 rows x (2 x 16 k)
  const int brow = tid >> 2, bchunk = tid & 3;  // B: 64 rows x (4 x 8 k)

  const float* asrc = X + (size_t)(bm * 128 + arow) * DM + aseg * 16;
  const _Float16* bsrc = WT + (size_t)(bn * 64 + brow) * DM + bchunk * 8;

  for (int k0 = 0; k0 < DM; k0 += 32) {
    // stage A (fp32 -> fp16)
    f32x4 v0 = *(const f32x4*)(asrc + k0);
    f32x4 v1 = *(const f32x4*)(asrc + k0 + 4);
    f32x4 v2 = *(const f32x4*)(asrc + k0 + 8);
    f32x4 v3 = *(const f32x4*)(asrc + k0 + 12);
    half8 h0, h1;
#pragma unroll
    for (int j = 0; j < 4; ++j) {
      h0[j] = (_Float16)v0[j]; h0[4 + j] = (_Float16)v1[j];
      h1[j] = (_Float16)v2[j]; h1[4 + j] = (_Float16)v3[j];
    }
    *(half8*)(AsB + arow * 64 + swz64(arow, aseg * 32)) = h0;
    *(half8*)(AsB + arow * 64 + swz64(arow, aseg * 32 + 16)) = h1;
    // stage B
    *(half8*)(BsB + brow * 64 + swz64(brow, bchunk * 16)) = *(const half8*)(bsrc + k0);
    __syncthreads();

    half8 af[4], bf[2];
#pragma unroll
    for (int m = 0; m < 4; ++m) {
      int r = wm * 64 + m * 16 + l15;
      af[m] = *(const half8*)(AsB + r * 64 + swz64(r, lg * 16));
    }
#pragma unroll
    for (int n = 0; n < 2; ++n) {
      int r = wn * 32 + n * 16 + l15;
      bf[n] = *(const half8*)(BsB + r * 64 + swz64(r, lg * 16));
    }
#pragma unroll
    for (int m = 0; m < 4; ++m)
#pragma unroll
      for (int n = 0; n < 2; ++n)
        acc[m][n] = __builtin_amdgcn_mfma_f32_16x16x32_f16(af[m], bf[n], acc[m][n], 0, 0, 0);
    __syncthreads();
  }

#pragma unroll
  for (int m = 0; m < 4; ++m)
#pragma unroll
    for (int n = 0; n < 2; ++n)
#pragma unroll
      for (int r = 0; r < 4; ++r) {
        int gm = bm * 128 + wm * 64 + m * 16 + lg * 4 + r;
        int gn = bn * 64 + wn * 32 + n * 16 + l15;
        int b = gm >> 11, s = gm & 2047;
        int h = gn >> 6, dd = gn & 63;
        _Float16 val = (_Float16)acc[m][n][r];
        if (z == 0)      Qo[((size_t)(b * NH + h) * SEQ + s) * DKV + dd] = val;
        else if (z == 1) Ko[((size_t)(b * NH + h) * SEQ + s) * DKV + dd] = val;
        else             Vto[((size_t)(b * NH + h) * DKV + dd) * SEQ + s] = val;
      }
}

// ---------------- flash attention: QBLK=64 (16/wave), KVBLK=64 ----------------
__global__ __launch_bounds__(256) void attn_kernel(
    const _Float16* __restrict__ Q, const _Float16* __restrict__ K, const _Float16* __restrict__ Vt,
    const float* __restrict__ biasT, const float* __restrict__ mask, _Float16* __restrict__ AO) {
  const int bh = blockIdx.y;
  const int b = bh / NH, h = bh - b * NH;
  const int q0 = blockIdx.x * 64;
  const int tid = threadIdx.x, lane = tid & 63, wave = tid >> 6;
  const int l15 = lane & 15, lg = lane >> 4;

  __shared__ alignas(16) _Float16 Ks[64 * 64];
  __shared__ alignas(16) _Float16 Vs[64 * 64];
  __shared__ alignas(16) _Float16 Ps[4][16 * 64];
  char* KsB = (char*)Ks;
  char* VsB = (char*)Vs;
  char* PsB = (char*)&Ps[wave][0];

  const size_t bhS = (size_t)(b * NH + h) * SEQ;

  // Q fragments held in registers for the whole kernel
  const _Float16* Qbase = Q + (bhS + q0 + wave * 16) * DKV;
  half8 qf0 = *(const half8*)(Qbase + (size_t)l15 * DKV + lg * 8);
  half8 qf1 = *(const half8*)(Qbase + (size_t)l15 * DKV + 32 + lg * 8);

  float m_r[4], l_r[4];
  f32x4 oacc[4] = {};
#pragma unroll
  for (int r = 0; r < 4; ++r) { m_r[r] = -1e30f; l_r[r] = 0.f; }

  const float* maskb = mask + (size_t)b * SEQ * SEQ;
  const float* biash = biasT + h * 4095;

  const int srow = tid >> 2;            // staging row 0..63
  const int sc = (tid & 3) * 32;        // byte offset of first 16B chunk in 128B row
  const _Float16* Vsrc0 = Vt + ((size_t)(b * NH + h) * DKV + srow) * SEQ;

  for (int kt = 0; kt < SEQ; kt += 64) {
    {
      const _Float16* ksrc = K + (bhS + kt + srow) * DKV + (sc >> 1);
      half8 kv0 = *(const half8*)ksrc;
      half8 kv1 = *(const half8*)(ksrc + 8);
      *(half8*)(KsB + srow * 128 + swz128(srow, sc)) = kv0;
      *(half8*)(KsB + srow * 128 + swz128(srow, sc + 16)) = kv1;
      const _Float16* vsrc = Vsrc0 + kt + (sc >> 1);
      half8 vv0 = *(const half8*)vsrc;
      half8 vv1 = *(const half8*)(vsrc + 8);
      *(half8*)(VsB + srow * 128 + swz128(srow, sc)) = vv0;
      *(half8*)(VsB + srow * 128 + swz128(srow, sc + 16)) = vv1;
    }
    __syncthreads();

    // S = Q K^T  (16 q-rows x 64 k-cols per wave)
    f32x4 sacc[4] = {};
#pragma unroll
    for (int nf = 0; nf < 4; ++nf) {
      int kr = nf * 16 + l15;
      half8 b0 = *(const half8*)(KsB + kr * 128 + swz128(kr, lg * 16));
      half8 b1 = *(const half8*)(KsB + kr * 128 + swz128(kr, 64 + lg * 16));
      sacc[nf] = __builtin_amdgcn_mfma_f32_16x16x32_f16(qf0, b0, sacc[nf], 0, 0, 0);
      sacc[nf] = __builtin_amdgcn_mfma_f32_16x16x32_f16(qf1, b1, sacc[nf], 0, 0, 0);
    }

    // bias + mask
    float sv[4][4];
#pragma unroll
    for (int nf = 0; nf < 4; ++nf) {
      int kk = kt + nf * 16 + l15;
#pragma unroll
      for (int r = 0; r < 4; ++r) {
        int qq = q0 + wave * 16 + lg * 4 + r;
        sv[nf][r] = sacc[nf][r] + biash[kk - qq + 2047] + maskb[(size_t)qq * SEQ + kk];
      }
    }

    // online softmax (row stats across 16 lanes of the group)
    float scale[4];
#pragma unroll
    for (int r = 0; r < 4; ++r) {
      float mx = fmaxf(fmaxf(sv[0][r], sv[1][r]), fmaxf(sv[2][r], sv[3][r]));
#pragma unroll
      for (int off = 1; off < 16; off <<= 1) mx = fmaxf(mx, __shfl_xor(mx, off));
      float mnew = fmaxf(m_r[r], mx);
      float sc_ = expf(m_r[r] - mnew);
      float rs = 0.f;
#pragma unroll
      for (int nf = 0; nf < 4; ++nf) { float p = expf(sv[nf][r] - mnew); sv[nf][r] = p; rs += p; }
#pragma unroll
      for (int off = 1; off < 16; off <<= 1) rs += __shfl_xor(rs, off);
      l_r[r] = l_r[r] * sc_ + rs;
      m_r[r] = mnew;
      scale[r] = sc_;
    }
#pragma unroll
    for (int df = 0; df < 4; ++df) {
      f32x4 t = oacc[df];
      t[0] *= scale[0]; t[1] *= scale[1]; t[2] *= scale[2]; t[3] *= scale[3];
      oacc[df] = t;
    }

    // P -> per-wave LDS (swizzled), then PV
#pragma unroll
    for (int nf = 0; nf < 4; ++nf)
#pragma unroll
      for (int r = 0; r < 4; ++r) {
        int prow = lg * 4 + r;
        int bcol = (nf * 16 + l15) * 2;
        *(_Float16*)(PsB + prow * 128 + (bcol ^ ((prow & 7) << 4))) = (_Float16)sv[nf][r];
      }
    __syncthreads();

#pragma unroll
    for (int ks = 0; ks < 2; ++ks) {
      half8 pa = *(const half8*)(PsB + l15 * 128 + ((ks * 64 + lg * 16) ^ ((l15 & 7) << 4)));
#pragma unroll
      for (int df = 0; df < 4; ++df) {
        int vr = df * 16 + l15;
        half8 vb = *(const half8*)(VsB + vr * 128 + swz128(vr, ks * 64 + lg * 16));
        oacc[df] = __builtin_amdgcn_mfma_f32_16x16x32_f16(pa, vb, oacc[df], 0, 0, 0);
      }
    }
    __syncthreads();
  }

  // epilogue: normalize + store attn_out fp16 [B, S, INNER]
#pragma unroll
  for (int df = 0; df < 4; ++df)
#pragma unroll
    for (int r = 0; r < 4; ++r) {
      int qq = q0 + wave * 16 + lg * 4 + r;
      int dd = df * 16 + l15;
      float v = oacc[df][r] / l_r[r];
      AO[((size_t)(b * SEQ + qq)) * INNER + h * DKV + dd] = (_Float16)v;
    }
}

// ---------------- output GEMM: AO[8192,384]f16 @ WO -> out fp32 ----------------
__global__ __launch_bounds__(256) void out_gemm(
    const _Float16* __restrict__ A, const _Float16* __restrict__ BT, float* __restrict__ C) {
  __shared__ alignas(16) _Float16 As[128 * 32];
  __shared__ alignas(16) _Float16 Bs[64 * 32];
  char* AsB = (char*)As;
  char* BsB = (char*)Bs;

  const int tid = threadIdx.x, lane = tid & 63, wave = tid >> 6;
  const int wm = wave >> 1, wn = wave & 1;
  const int bm = blockIdx.x, bn = blockIdx.y;
  const int l15 = lane & 15, lg = lane >> 4;

  f32x4 acc[4][2] = {};
  const int arow = tid >> 1, aseg = tid & 1;
  const int brow = tid >> 2, bchunk = tid & 3;
  const _Float16* asrc = A + (size_t)(bm * 128 + arow) * INNER + aseg * 16;
  const _Float16* bsrc = BT + (size_t)(bn * 64 + brow) * INNER + bchunk * 8;

  for (int k0 = 0; k0 < INNER; k0 += 32) {
    half8 a0 = *(const half8*)(asrc + k0);
    half8 a1 = *(const half8*)(asrc + k0 + 8);
    *(half8*)(AsB + arow * 64 + swz64(arow, aseg * 32)) = a0;
    *(half8*)(AsB + arow * 64 + swz64(arow, aseg * 32 + 16)) = a1;
    *(half8*)(BsB + brow * 64 + swz64(brow, bchunk * 16)) = *(const half8*)(bsrc + k0);
    __syncthreads();

    half8 af[4], bf[2];
#pragma unroll
    for (int m = 0; m < 4; ++m) {
      int r = wm * 64 + m * 16 + l15;
      af[m] = *(const half8*)(AsB + r * 64 + swz64(r, lg * 16));
    }
#pragma unroll
    for (int n = 0; n < 2; ++n) {
      int r = wn * 32 + n * 16 + l15;
      bf[n] = *(const half8*)(BsB + r * 64 + swz64(r, lg * 16));
    }
#pragma unroll
    for (int m = 0; m < 4; ++m)
#pragma unroll
      for (int n = 0; n < 2; ++n)
        acc[m][n] = __builtin_amdgcn_mfma_f32_16x16x32_f16(af[m], bf[n], acc[m][n], 0, 0, 0);
    __syncthreads();
  }

#pragma unroll
  for (int m = 0; m < 4; ++m)
#pragma unroll
    for (int n = 0; n < 2; ++n)
#pragma unroll
      for (int r = 0; r < 4; ++r) {
        int gm = bm * 128 + wm * 64 + m * 16 + lg * 4 + r;
        int gn = bn * 64 + wn * 32 + n * 16 + l15;
        C[(size_t)gm * DM + gn] = acc[m][n][r];
      }
}

// ---------------- launch ----------------
extern "C" void kernel_launch(void* const* d_in, const int* in_sizes, int n_in,
                              void* d_out, int out_size, void* d_ws, size_t ws_size,
                              hipStream_t stream) {
  const float* kv   = (const float*)d_in[0];
  const float* qs   = (const float*)d_in[1];
  const float* mask = (const float*)d_in[2];
  const float* WQ   = (const float*)d_in[3];
  const float* WK   = (const float*)d_in[4];
  const float* WV   = (const float*)d_in[5];
  const float* WO   = (const float*)d_in[6];
  const float* rb   = (const float*)d_in[7];
  float* out = (float*)d_out;
  char* ws = (char*)d_ws;

  const size_t WT_BYTES  = (size_t)INNER * DM * 2;             // 1,130,496
  const size_t QKV_BYTES = (size_t)BATCH * NH * SEQ * DKV * 2; // 6,291,456
  _Float16* WqT = (_Float16*)(ws);
  _Float16* WkT = (_Float16*)(ws + WT_BYTES);
  _Float16* WvT = (_Float16*)(ws + 2 * WT_BYTES);
  _Float16* WoT = (_Float16*)(ws + 3 * WT_BYTES);
  _Float16* Qh  = (_Float16*)(ws + 4 * WT_BYTES);
  _Float16* Kh  = (_Float16*)(ws + 4 * WT_BYTES + QKV_BYTES);
  _Float16* Vth = (_Float16*)(ws + 4 * WT_BYTES + 2 * QKV_BYTES);
  _Float16* AO  = (_Float16*)(ws + 4 * WT_BYTES + 3 * QKV_BYTES);
  float* biasT  = (float*)(ws + 4 * WT_BYTES + 4 * QKV_BYTES);

  hipLaunchKernelGGL(prep_weights, dim3((4 * DM * INNER + 255) / 256), dim3(256), 0, stream,
                     WQ, WK, WV, WO, WqT, WkT, WvT, WoT);
  hipLaunchKernelGGL(prep_bias, dim3((NH * 4095 + 255) / 256), dim3(256), 0, stream, rb, biasT);
  hipLaunchKernelGGL(proj_gemm, dim3(64, 6, 3), dim3(256), 0, stream,
                     qs, kv, WqT, WkT, WvT, Qh, Kh, Vth);
  hipLaunchKernelGGL(attn_kernel, dim3(32, 24), dim3(256), 0, stream,
                     Qh, Kh, Vth, biasT, mask, AO);
  hipLaunchKernelGGL(out_gemm, dim3(64, 23), dim3(256), 0, stream, AO, WoT, out);
}

// Round 2
// 221.798 us; speedup vs baseline: 1.4992x; 1.4992x over previous
//
#include <hip/hip_runtime.h>
#include <hip/hip_fp16.h>
#include <cstdint>

#define DM    1472
#define NH    6
#define DKV   64
#define INNER 384
#define BATCH 4
#define SEQ   2048
#define LOG2E 1.4426950408889634f

typedef __attribute__((ext_vector_type(8))) _Float16 half8;
typedef __attribute__((ext_vector_type(4))) _Float16 half4;
typedef __attribute__((ext_vector_type(4))) float f32x4;

__device__ __forceinline__ int swz64(int row, int b)  { return b ^ (((row >> 1) & 3) << 4); }
__device__ __forceinline__ int swz128(int row, int b) { return b ^ ((row & 7) << 4); }

// ---------------- prep: weights fp32 -> fp16 transposed ----------------
__global__ void prep_weights(const float* __restrict__ WQ, const float* __restrict__ WK,
                             const float* __restrict__ WV, const float* __restrict__ WO,
                             _Float16* __restrict__ WqT, _Float16* __restrict__ WkT,
                             _Float16* __restrict__ WvT, _Float16* __restrict__ WoT) {
  int idx = blockIdx.x * blockDim.x + threadIdx.x;
  const int per = DM * INNER;
  if (idx >= 4 * per) return;
  int which = idx / per;
  int i = idx - which * per;
  if (which < 3) {
    const float* W = which == 0 ? WQ : (which == 1 ? WK : WV);
    _Float16* T = which == 0 ? WqT : (which == 1 ? WkT : WvT);
    int k = i / INNER, n = i - (i / INNER) * INNER;
    T[(size_t)n * DM + k] = (_Float16)W[i];   // [INNER][DM] = W^T
  } else {
    int k = i / DM, n = i - (i / DM) * DM;
    WoT[(size_t)n * INNER + k] = (_Float16)WO[i];  // [DM][INNER] = WO^T
  }
}

// ---------------- prep: shift-replicated bias table biasS[h][c][4104] ----------------
// biasS[h][c][i] = bias(j = i + c) * LOG2E, so that values base..base+3 are one
// aligned float4 at table c = base&3, index base&~3. Buckets from exact fp32 thresholds.
__global__ void prep_bias(const float* __restrict__ rel_bias, float* __restrict__ biasS) {
  int idx = blockIdx.x * blockDim.x + threadIdx.x;
  const int TOT = NH * 4 * 4104;
  if (idx >= TOT) return;
  int h = idx / (4 * 4104);
  int rem = idx - h * 4 * 4104;
  int cc = rem / 4104;
  int i = rem - cc * 4104;
  int j = i + cc; if (j > 4094) j = 4094;
  int d = j - 2047;                 // relative position k - q
  int ret = d > 0 ? 16 : 0;
  int a = d < 0 ? -d : d;
  int bucket;
  if (a < 8) bucket = ret + a;
  else {
    int large;
    if      (a >= 91) large = 15;
    else if (a >= 64) large = 14;
    else if (a >= 46) large = 13;
    else if (a >= 32) large = 12;
    else if (a >= 23) large = 11;
    else if (a >= 16) large = 10;
    else if (a >= 12) large = 9;
    else              large = 8;
    bucket = ret + large;
  }
  biasS[idx] = rel_bias[bucket * NH + h] * LOG2E;
}

// ---------------- projection GEMM: X[8192,1472]fp32 @ W -> Q/K/V fp16 ----------------
// z=0: Q (scaled by LOG2E), z=1: K, z=2: V^T
__global__ __launch_bounds__(256) void proj_gemm(
    const float* __restrict__ Xq, const float* __restrict__ Xkv,
    const _Float16* __restrict__ WqT, const _Float16* __restrict__ WkT, const _Float16* __restrict__ WvT,
    _Float16* __restrict__ Qo, _Float16* __restrict__ Ko, _Float16* __restrict__ Vto) {
  const int z = blockIdx.z;
  const float* __restrict__ X = (z == 0) ? Xq : Xkv;
  const _Float16* __restrict__ WT = (z == 0) ? WqT : (z == 1 ? WkT : WvT);

  __shared__ alignas(16) _Float16 As[128 * 32];
  __shared__ alignas(16) _Float16 Bs[64 * 32];
  char* AsB = (char*)As;
  char* BsB = (char*)Bs;

  const int tid = threadIdx.x;
  const int lane = tid & 63, wave = tid >> 6;
  const int wm = wave >> 1, wn = wave & 1;
  const int bm = blockIdx.x, bn = blockIdx.y;
  const int l15 = lane & 15, lg = lane >> 4;

  f32x4 acc[4][2] = {};

  const int arow = tid >> 1, aseg = tid & 1;
  const int brow = tid >> 2, bchunk = tid & 3;

  const float* asrc = X + (size_t)(bm * 128 + arow) * DM + aseg * 16;
  const _Float16* bsrc = WT + (size_t)(bn * 64 + brow) * DM + bchunk * 8;

  for (int k0 = 0; k0 < DM; k0 += 32) {
    f32x4 v0 = *(const f32x4*)(asrc + k0);
    f32x4 v1 = *(const f32x4*)(asrc + k0 + 4);
    f32x4 v2 = *(const f32x4*)(asrc + k0 + 8);
    f32x4 v3 = *(const f32x4*)(asrc + k0 + 12);
    half8 h0, h1;
#pragma unroll
    for (int j = 0; j < 4; ++j) {
      h0[j] = (_Float16)v0[j]; h0[4 + j] = (_Float16)v1[j];
      h1[j] = (_Float16)v2[j]; h1[4 + j] = (_Float16)v3[j];
    }
    *(half8*)(AsB + arow * 64 + swz64(arow, aseg * 32)) = h0;
    *(half8*)(AsB + arow * 64 + swz64(arow, aseg * 32 + 16)) = h1;
    *(half8*)(BsB + brow * 64 + swz64(brow, bchunk * 16)) = *(const half8*)(bsrc + k0);
    __syncthreads();

    half8 af[4], bf[2];
#pragma unroll
    for (int m = 0; m < 4; ++m) {
      int r = wm * 64 + m * 16 + l15;
      af[m] = *(const half8*)(AsB + r * 64 + swz64(r, lg * 16));
    }
#pragma unroll
    for (int n = 0; n < 2; ++n) {
      int r = wn * 32 + n * 16 + l15;
      bf[n] = *(const half8*)(BsB + r * 64 + swz64(r, lg * 16));
    }
#pragma unroll
    for (int m = 0; m < 4; ++m)
#pragma unroll
      for (int n = 0; n < 2; ++n)
        acc[m][n] = __builtin_amdgcn_mfma_f32_16x16x32_f16(af[m], bf[n], acc[m][n], 0, 0, 0);
    __syncthreads();
  }

#pragma unroll
  for (int m = 0; m < 4; ++m)
#pragma unroll
    for (int n = 0; n < 2; ++n)
#pragma unroll
      for (int r = 0; r < 4; ++r) {
        int gm = bm * 128 + wm * 64 + m * 16 + lg * 4 + r;
        int gn = bn * 64 + wn * 32 + n * 16 + l15;
        int b = gm >> 11, s = gm & 2047;
        int h = gn >> 6, dd = gn & 63;
        float av = acc[m][n][r];
        if (z == 0)      Qo[((size_t)(b * NH + h) * SEQ + s) * DKV + dd] = (_Float16)(av * LOG2E);
        else if (z == 1) Ko[((size_t)(b * NH + h) * SEQ + s) * DKV + dd] = (_Float16)av;
        else             Vto[((size_t)(b * NH + h) * DKV + dd) * SEQ + s] = (_Float16)av;
      }
}

// ---------------- flash attention, swapped QK^T: S^T[k][q] per lane ----------------
__global__ __launch_bounds__(256) void attn_kernel(
    const _Float16* __restrict__ Q, const _Float16* __restrict__ K, const _Float16* __restrict__ Vt,
    const float* __restrict__ biasS, const float* __restrict__ mask, _Float16* __restrict__ AO) {
  // XCD swizzle: 768 blocks = 8 XCDs x 96; each XCD gets 3 consecutive bh (K/V L2-resident)
  const int bid = blockIdx.x;
  const int g = (bid & 7) * 96 + (bid >> 3);
  const int bh = g >> 5, qb = g & 31;
  const int b = bh / NH, h = bh - b * NH;
  const int q0 = qb * 64;
  const int tid = threadIdx.x, lane = tid & 63, wave = tid >> 6;
  const int l15 = lane & 15, lg = lane >> 4;

  __shared__ alignas(16) _Float16 Ks[2][64 * 64];
  __shared__ alignas(16) _Float16 Vs[2][64 * 64];
  __shared__ alignas(16) _Float16 Ps[4][16 * 72];   // 144B rows (pad) per wave

  const size_t bhS = (size_t)bh * SEQ;
  const int qq = q0 + wave * 16 + l15;   // this lane's q column

  // Q fragments in registers (Q pre-scaled by LOG2E)
  const _Float16* Qbase = Q + (bhS + q0 + wave * 16) * DKV;
  half8 qf0 = *(const half8*)(Qbase + (size_t)l15 * DKV + lg * 8);
  half8 qf1 = *(const half8*)(Qbase + (size_t)l15 * DKV + 32 + lg * 8);

  const float* maskrow = mask + (size_t)b * SEQ * SEQ + (size_t)qq * SEQ;
  const int c = (3 - l15) & 3;           // alignment class, constant per lane
  const float* bptr[4];
#pragma unroll
  for (int nf = 0; nf < 4; ++nf)
    bptr[nf] = biasS + (size_t)(h * 4 + c) * 4104 + (nf * 16 + lg * 4 - qq + 2047 - c);

  float m_r = -1e30f, l_r = 0.f;
  f32x4 oacc[4] = {};

  const int srow = tid >> 2;             // staging row 0..63
  const int scb = (tid & 3) * 32;        // byte offset of first 16B chunk
  const _Float16* Ksrc = K + (bhS + srow) * DKV + (scb >> 1);
  const _Float16* Vsrc = Vt + ((size_t)bh * DKV + srow) * SEQ + (scb >> 1);

  // prologue: stage tile 0 into buf 0
  {
    half8 k0v = *(const half8*)(Ksrc);
    half8 k1v = *(const half8*)(Ksrc + 8);
    half8 v0v = *(const half8*)(Vsrc);
    half8 v1v = *(const half8*)(Vsrc + 8);
    char* KsW = (char*)&Ks[0][0];
    char* VsW = (char*)&Vs[0][0];
    *(half8*)(KsW + srow * 128 + swz128(srow, scb)) = k0v;
    *(half8*)(KsW + srow * 128 + swz128(srow, scb + 16)) = k1v;
    *(half8*)(VsW + srow * 128 + swz128(srow, scb)) = v0v;
    *(half8*)(VsW + srow * 128 + swz128(srow, scb + 16)) = v1v;
  }

  for (int t = 0; t < SEQ / 64; ++t) {
    __syncthreads();
    const int kt = t * 64;
    const bool pre = (t + 1 < SEQ / 64);
    half8 knA, knB, vnA, vnB;
    if (pre) {
      const _Float16* kp = Ksrc + (size_t)(kt + 64) * DKV;
      knA = *(const half8*)(kp);
      knB = *(const half8*)(kp + 8);
      const _Float16* vp = Vsrc + kt + 64;
      vnA = *(const half8*)(vp);
      vnB = *(const half8*)(vp + 8);
    }
    const char* KsB = (const char*)&Ks[t & 1][0];
    const char* VsB = (const char*)&Vs[t & 1][0];
    char* PsB = (char*)&Ps[wave][0];

    // S^T = K Q^T : rows k, cols q
    f32x4 sacc[4] = {};
    __builtin_amdgcn_s_setprio(1);
#pragma unroll
    for (int nf = 0; nf < 4; ++nf) {
      int kr = nf * 16 + l15;
      half8 kf0 = *(const half8*)(KsB + kr * 128 + swz128(kr, lg * 16));
      half8 kf1 = *(const half8*)(KsB + kr * 128 + swz128(kr, 64 + lg * 16));
      sacc[nf] = __builtin_amdgcn_mfma_f32_16x16x32_f16(kf0, qf0, sacc[nf], 0, 0, 0);
      sacc[nf] = __builtin_amdgcn_mfma_f32_16x16x32_f16(kf1, qf1, sacc[nf], 0, 0, 0);
    }
    __builtin_amdgcn_s_setprio(0);

    // bias (prescaled, aligned float4) + mask (float4) + max
    float sv[4][4];
    float mx = -1e30f;
#pragma unroll
    for (int nf = 0; nf < 4; ++nf) {
      f32x4 bv = *(const f32x4*)(bptr[nf] + kt);
      f32x4 mv = *(const f32x4*)(maskrow + kt + nf * 16 + lg * 4);
#pragma unroll
      for (int r = 0; r < 4; ++r) {
        float s = sacc[nf][r] + bv[r] + mv[r] * LOG2E;
        sv[nf][r] = s;
        mx = fmaxf(mx, s);
      }
    }
    mx = fmaxf(mx, __shfl_xor(mx, 16));
    mx = fmaxf(mx, __shfl_xor(mx, 32));
    const float mnew = fmaxf(m_r, mx);
    const float sc_ = __builtin_amdgcn_exp2f(m_r - mnew);
    float rs = 0.f;
#pragma unroll
    for (int nf = 0; nf < 4; ++nf) {
      half4 ph;
#pragma unroll
      for (int r = 0; r < 4; ++r) {
        float p = __builtin_amdgcn_exp2f(sv[nf][r] - mnew);
        rs += p;
        ph[r] = (_Float16)p;
      }
      *(half4*)(PsB + l15 * 144 + nf * 32 + lg * 8) = ph;   // P[q][k], rows padded
    }
    rs += __shfl_xor(rs, 16);
    rs += __shfl_xor(rs, 32);
    l_r = l_r * sc_ + rs;
    m_r = mnew;

    // broadcast scale from q-column lanes to o-row layout, rescale O
    f32x4 scv;
#pragma unroll
    for (int r = 0; r < 4; ++r) scv[r] = __shfl(sc_, lg * 4 + r);
#pragma unroll
    for (int df = 0; df < 4; ++df) oacc[df] *= scv;

    // O += P V
    __builtin_amdgcn_s_setprio(1);
#pragma unroll
    for (int ks = 0; ks < 2; ++ks) {
      half8 pa = *(const half8*)(PsB + l15 * 144 + ks * 64 + lg * 16);
#pragma unroll
      for (int df = 0; df < 4; ++df) {
        int vr = df * 16 + l15;
        half8 vb = *(const half8*)(VsB + vr * 128 + swz128(vr, ks * 64 + lg * 16));
        oacc[df] = __builtin_amdgcn_mfma_f32_16x16x32_f16(pa, vb, oacc[df], 0, 0, 0);
      }
    }
    __builtin_amdgcn_s_setprio(0);

    if (pre) {
      char* KsW = (char*)&Ks[(t + 1) & 1][0];
      char* VsW = (char*)&Vs[(t + 1) & 1][0];
      *(half8*)(KsW + srow * 128 + swz128(srow, scb)) = knA;
      *(half8*)(KsW + srow * 128 + swz128(srow, scb + 16)) = knB;
      *(half8*)(VsW + srow * 128 + swz128(srow, scb)) = vnA;
      *(half8*)(VsW + srow * 128 + swz128(srow, scb + 16)) = vnB;
    }
  }

  // epilogue: broadcast l to o-row layout, normalize, store
  f32x4 lv;
#pragma unroll
  for (int r = 0; r < 4; ++r) lv[r] = __shfl(l_r, lg * 4 + r);
#pragma unroll
  for (int df = 0; df < 4; ++df) {
    int dd = df * 16 + l15;
#pragma unroll
    for (int r = 0; r < 4; ++r) {
      int qrow = q0 + wave * 16 + lg * 4 + r;
      AO[((size_t)(b * SEQ + qrow)) * INNER + h * DKV + dd] = (_Float16)(oacc[df][r] / lv[r]);
    }
  }
}

// ---------------- output GEMM: AO[8192,384]f16 @ WO -> out fp32 ----------------
__global__ __launch_bounds__(256) void out_gemm(
    const _Float16* __restrict__ A, const _Float16* __restrict__ BT, float* __restrict__ C) {
  __shared__ alignas(16) _Float16 As[128 * 32];
  __shared__ alignas(16) _Float16 Bs[64 * 32];
  char* AsB = (char*)As;
  char* BsB = (char*)Bs;

  const int tid = threadIdx.x, lane = tid & 63, wave = tid >> 6;
  const int wm = wave >> 1, wn = wave & 1;
  const int bm = blockIdx.x, bn = blockIdx.y;
  const int l15 = lane & 15, lg = lane >> 4;

  f32x4 acc[4][2] = {};
  const int arow = tid >> 1, aseg = tid & 1;
  const int brow = tid >> 2, bchunk = tid & 3;
  const _Float16* asrc = A + (size_t)(bm * 128 + arow) * INNER + aseg * 16;
  const _Float16* bsrc = BT + (size_t)(bn * 64 + brow) * INNER + bchunk * 8;

  for (int k0 = 0; k0 < INNER; k0 += 32) {
    half8 a0 = *(const half8*)(asrc + k0);
    half8 a1 = *(const half8*)(asrc + k0 + 8);
    *(half8*)(AsB + arow * 64 + swz64(arow, aseg * 32)) = a0;
    *(half8*)(AsB + arow * 64 + swz64(arow, aseg * 32 + 16)) = a1;
    *(half8*)(BsB + brow * 64 + swz64(brow, bchunk * 16)) = *(const half8*)(bsrc + k0);
    __syncthreads();

    half8 af[4], bf[2];
#pragma unroll
    for (int m = 0; m < 4; ++m) {
      int r = wm * 64 + m * 16 + l15;
      af[m] = *(const half8*)(AsB + r * 64 + swz64(r, lg * 16));
    }
#pragma unroll
    for (int n = 0; n < 2; ++n) {
      int r = wn * 32 + n * 16 + l15;
      bf[n] = *(const half8*)(BsB + r * 64 + swz64(r, lg * 16));
    }
#pragma unroll
    for (int m = 0; m < 4; ++m)
#pragma unroll
      for (int n = 0; n < 2; ++n)
        acc[m][n] = __builtin_amdgcn_mfma_f32_16x16x32_f16(af[m], bf[n], acc[m][n], 0, 0, 0);
    __syncthreads();
  }

#pragma unroll
  for (int m = 0; m < 4; ++m)
#pragma unroll
    for (int n = 0; n < 2; ++n)
#pragma unroll
      for (int r = 0; r < 4; ++r) {
        int gm = bm * 128 + wm * 64 + m * 16 + lg * 4 + r;
        int gn = bn * 64 + wn * 32 + n * 16 + l15;
        C[(size_t)gm * DM + gn] = acc[m][n][r];
      }
}

// ---------------- launch ----------------
extern "C" void kernel_launch(void* const* d_in, const int* in_sizes, int n_in,
                              void* d_out, int out_size, void* d_ws, size_t ws_size,
                              hipStream_t stream) {
  const float* kv   = (const float*)d_in[0];
  const float* qs   = (const float*)d_in[1];
  const float* mask = (const float*)d_in[2];
  const float* WQ   = (const float*)d_in[3];
  const float* WK   = (const float*)d_in[4];
  const float* WV   = (const float*)d_in[5];
  const float* WO   = (const float*)d_in[6];
  const float* rb   = (const float*)d_in[7];
  float* out = (float*)d_out;
  char* ws = (char*)d_ws;

  const size_t WT_BYTES  = (size_t)INNER * DM * 2;
  const size_t QKV_BYTES = (size_t)BATCH * NH * SEQ * DKV * 2;
  _Float16* WqT = (_Float16*)(ws);
  _Float16* WkT = (_Float16*)(ws + WT_BYTES);
  _Float16* WvT = (_Float16*)(ws + 2 * WT_BYTES);
  _Float16* WoT = (_Float16*)(ws + 3 * WT_BYTES);
  _Float16* Qh  = (_Float16*)(ws + 4 * WT_BYTES);
  _Float16* Kh  = (_Float16*)(ws + 4 * WT_BYTES + QKV_BYTES);
  _Float16* Vth = (_Float16*)(ws + 4 * WT_BYTES + 2 * QKV_BYTES);
  _Float16* AO  = (_Float16*)(ws + 4 * WT_BYTES + 3 * QKV_BYTES);
  float* biasS  = (float*)(ws + 4 * WT_BYTES + 4 * QKV_BYTES);

  hipLaunchKernelGGL(prep_weights, dim3((4 * DM * INNER + 255) / 256), dim3(256), 0, stream,
                     WQ, WK, WV, WO, WqT, WkT, WvT, WoT);
  hipLaunchKernelGGL(prep_bias, dim3((NH * 4 * 4104 + 255) / 256), dim3(256), 0, stream, rb, biasS);
  hipLaunchKernelGGL(proj_gemm, dim3(64, 6, 3), dim3(256), 0, stream,
                     qs, kv, WqT, WkT, WvT, Qh, Kh, Vth);
  hipLaunchKernelGGL(attn_kernel, dim3(768), dim3(256), 0, stream,
                     Qh, Kh, Vth, biasS, mask, AO);
  hipLaunchKernelGGL(out_gemm, dim3(64, 23), dim3(256), 0, stream, AO, WoT, out);
}

// Round 3
// 209.734 us; speedup vs baseline: 1.5855x; 1.0575x over previous
//
#include <hip/hip_runtime.h>
#include <hip/hip_fp16.h>
#include <cstdint>

#define DM    1472
#define NH    6
#define DKV   64
#define INNER 384
#define BATCH 4
#define SEQ   2048
#define LOG2E 1.4426950408889634f

typedef __attribute__((ext_vector_type(8))) _Float16 half8;
typedef __attribute__((ext_vector_type(4))) _Float16 half4;
typedef __attribute__((ext_vector_type(4))) float f32x4;

__device__ __forceinline__ int swz64(int row, int b)  { return b ^ (((row >> 1) & 3) << 4); }
__device__ __forceinline__ int swz128(int row, int b) { return b ^ ((row & 7) << 4); }

// ---------------- prep: weights fp32 -> fp16 transposed ----------------
__global__ void prep_weights(const float* __restrict__ WQ, const float* __restrict__ WK,
                             const float* __restrict__ WV, const float* __restrict__ WO,
                             _Float16* __restrict__ WqT, _Float16* __restrict__ WkT,
                             _Float16* __restrict__ WvT, _Float16* __restrict__ WoT) {
  int idx = blockIdx.x * blockDim.x + threadIdx.x;
  const int per = DM * INNER;
  if (idx >= 4 * per) return;
  int which = idx / per;
  int i = idx - which * per;
  if (which < 3) {
    const float* W = which == 0 ? WQ : (which == 1 ? WK : WV);
    _Float16* T = which == 0 ? WqT : (which == 1 ? WkT : WvT);
    int k = i / INNER, n = i - (i / INNER) * INNER;
    T[(size_t)n * DM + k] = (_Float16)W[i];   // [INNER][DM] = W^T
  } else {
    int k = i / DM, n = i - (i / DM) * DM;
    WoT[(size_t)n * INNER + k] = (_Float16)WO[i];  // [DM][INNER] = WO^T
  }
}

// ---------------- prep: shift-replicated bias table biasS[h][c][4104] ----------------
__global__ void prep_bias(const float* __restrict__ rel_bias, float* __restrict__ biasS) {
  int idx = blockIdx.x * blockDim.x + threadIdx.x;
  const int TOT = NH * 4 * 4104;
  if (idx >= TOT) return;
  int h = idx / (4 * 4104);
  int rem = idx - h * 4 * 4104;
  int cc = rem / 4104;
  int i = rem - cc * 4104;
  int j = i + cc; if (j > 4094) j = 4094;
  int d = j - 2047;                 // relative position k - q
  int ret = d > 0 ? 16 : 0;
  int a = d < 0 ? -d : d;
  int bucket;
  if (a < 8) bucket = ret + a;
  else {
    int large;
    if      (a >= 91) large = 15;
    else if (a >= 64) large = 14;
    else if (a >= 46) large = 13;
    else if (a >= 32) large = 12;
    else if (a >= 23) large = 11;
    else if (a >= 16) large = 10;
    else if (a >= 12) large = 9;
    else              large = 8;
    bucket = ret + large;
  }
  biasS[idx] = rel_bias[bucket * NH + h] * LOG2E;
}

// ---------------- projection GEMM: 128x128x32 double-buffered ----------------
// z=0: Q (scaled by LOG2E), z=1: K, z=2: V^T
__global__ __launch_bounds__(256) void proj_gemm(
    const float* __restrict__ Xq, const float* __restrict__ Xkv,
    const _Float16* __restrict__ WqT, const _Float16* __restrict__ WkT, const _Float16* __restrict__ WvT,
    _Float16* __restrict__ Qo, _Float16* __restrict__ Ko, _Float16* __restrict__ Vto) {
  const int z = blockIdx.z;
  const float* __restrict__ X = (z == 0) ? Xq : Xkv;
  const _Float16* __restrict__ WT = (z == 0) ? WqT : (z == 1 ? WkT : WvT);

  __shared__ alignas(16) _Float16 As[2][128 * 32];
  __shared__ alignas(16) _Float16 Bs[2][128 * 32];

  const int tid = threadIdx.x;
  const int lane = tid & 63, wave = tid >> 6;
  const int wm = wave >> 1, wn = wave & 1;
  const int bm = blockIdx.x, bn = blockIdx.y;
  const int l15 = lane & 15, lg = lane >> 4;

  f32x4 acc[4][4] = {};

  const int arow = tid >> 1, aseg = tid & 1;   // A: 128 rows x (2 x 16 k)
  const int brow = tid >> 1, bseg = tid & 1;   // B: 128 rows x (2 x 16 k)

  const float* asrc = X + (size_t)(bm * 128 + arow) * DM + aseg * 16;
  const _Float16* bsrc = WT + (size_t)(bn * 128 + brow) * DM + bseg * 16;

  const int NT = DM / 32;   // 46

  // prologue: stage tile 0 into buf 0
  {
    f32x4 v0 = *(const f32x4*)(asrc);
    f32x4 v1 = *(const f32x4*)(asrc + 4);
    f32x4 v2 = *(const f32x4*)(asrc + 8);
    f32x4 v3 = *(const f32x4*)(asrc + 12);
    half8 b0 = *(const half8*)(bsrc);
    half8 b1 = *(const half8*)(bsrc + 8);
    half8 h0, h1;
#pragma unroll
    for (int j = 0; j < 4; ++j) {
      h0[j] = (_Float16)v0[j]; h0[4 + j] = (_Float16)v1[j];
      h1[j] = (_Float16)v2[j]; h1[4 + j] = (_Float16)v3[j];
    }
    char* AsW = (char*)&As[0][0];
    char* BsW = (char*)&Bs[0][0];
    *(half8*)(AsW + arow * 64 + swz64(arow, aseg * 32)) = h0;
    *(half8*)(AsW + arow * 64 + swz64(arow, aseg * 32 + 16)) = h1;
    *(half8*)(BsW + brow * 64 + swz64(brow, bseg * 32)) = b0;
    *(half8*)(BsW + brow * 64 + swz64(brow, bseg * 32 + 16)) = b1;
  }

  for (int t = 0; t < NT; ++t) {
    __syncthreads();
    const bool pre = (t + 1 < NT);
    f32x4 v0, v1, v2, v3;
    half8 nb0, nb1;
    if (pre) {
      const int kn = (t + 1) * 32;
      v0 = *(const f32x4*)(asrc + kn);
      v1 = *(const f32x4*)(asrc + kn + 4);
      v2 = *(const f32x4*)(asrc + kn + 8);
      v3 = *(const f32x4*)(asrc + kn + 12);
      nb0 = *(const half8*)(bsrc + kn);
      nb1 = *(const half8*)(bsrc + kn + 8);
    }

    const char* AsB = (const char*)&As[t & 1][0];
    const char* BsB = (const char*)&Bs[t & 1][0];
    half8 af[4], bf[4];
#pragma unroll
    for (int m = 0; m < 4; ++m) {
      int r = wm * 64 + m * 16 + l15;
      af[m] = *(const half8*)(AsB + r * 64 + swz64(r, lg * 16));
    }
#pragma unroll
    for (int n = 0; n < 4; ++n) {
      int r = wn * 64 + n * 16 + l15;
      bf[n] = *(const half8*)(BsB + r * 64 + swz64(r, lg * 16));
    }
    __builtin_amdgcn_s_setprio(1);
#pragma unroll
    for (int m = 0; m < 4; ++m)
#pragma unroll
      for (int n = 0; n < 4; ++n)
        acc[m][n] = __builtin_amdgcn_mfma_f32_16x16x32_f16(af[m], bf[n], acc[m][n], 0, 0, 0);
    __builtin_amdgcn_s_setprio(0);

    if (pre) {
      half8 h0, h1;
#pragma unroll
      for (int j = 0; j < 4; ++j) {
        h0[j] = (_Float16)v0[j]; h0[4 + j] = (_Float16)v1[j];
        h1[j] = (_Float16)v2[j]; h1[4 + j] = (_Float16)v3[j];
      }
      char* AsW = (char*)&As[(t + 1) & 1][0];
      char* BsW = (char*)&Bs[(t + 1) & 1][0];
      *(half8*)(AsW + arow * 64 + swz64(arow, aseg * 32)) = h0;
      *(half8*)(AsW + arow * 64 + swz64(arow, aseg * 32 + 16)) = h1;
      *(half8*)(BsW + brow * 64 + swz64(brow, bseg * 32)) = nb0;
      *(half8*)(BsW + brow * 64 + swz64(brow, bseg * 32 + 16)) = nb1;
    }
  }

#pragma unroll
  for (int m = 0; m < 4; ++m)
#pragma unroll
    for (int n = 0; n < 4; ++n)
#pragma unroll
      for (int r = 0; r < 4; ++r) {
        int gm = bm * 128 + wm * 64 + m * 16 + lg * 4 + r;
        int gn = bn * 128 + wn * 64 + n * 16 + l15;
        int b = gm >> 11, s = gm & 2047;
        int h = gn >> 6, dd = gn & 63;
        float av = acc[m][n][r];
        if (z == 0)      Qo[((size_t)(b * NH + h) * SEQ + s) * DKV + dd] = (_Float16)(av * LOG2E);
        else if (z == 1) Ko[((size_t)(b * NH + h) * SEQ + s) * DKV + dd] = (_Float16)av;
        else             Vto[((size_t)(b * NH + h) * DKV + dd) * SEQ + s] = (_Float16)av;
      }
}

// ---------------- flash attention, swapped QK^T: S^T[k][q] per lane ----------------
__global__ __launch_bounds__(256) void attn_kernel(
    const _Float16* __restrict__ Q, const _Float16* __restrict__ K, const _Float16* __restrict__ Vt,
    const float* __restrict__ biasS, const float* __restrict__ mask, _Float16* __restrict__ AO) {
  const int bid = blockIdx.x;
  const int g = (bid & 7) * 96 + (bid >> 3);
  const int bh = g >> 5, qb = g & 31;
  const int b = bh / NH, h = bh - b * NH;
  const int q0 = qb * 64;
  const int tid = threadIdx.x, lane = tid & 63, wave = tid >> 6;
  const int l15 = lane & 15, lg = lane >> 4;

  __shared__ alignas(16) _Float16 Ks[2][64 * 64];
  __shared__ alignas(16) _Float16 Vs[2][64 * 64];
  __shared__ alignas(16) _Float16 Ps[4][16 * 72];   // 144B rows (pad) per wave

  const size_t bhS = (size_t)bh * SEQ;
  const int qq = q0 + wave * 16 + l15;

  const _Float16* Qbase = Q + (bhS + q0 + wave * 16) * DKV;
  half8 qf0 = *(const half8*)(Qbase + (size_t)l15 * DKV + lg * 8);
  half8 qf1 = *(const half8*)(Qbase + (size_t)l15 * DKV + 32 + lg * 8);

  const float* maskrow = mask + (size_t)b * SEQ * SEQ + (size_t)qq * SEQ;
  const int c = (3 - l15) & 3;
  const float* bptr[4];
#pragma unroll
  for (int nf = 0; nf < 4; ++nf)
    bptr[nf] = biasS + (size_t)(h * 4 + c) * 4104 + (nf * 16 + lg * 4 - qq + 2047 - c);

  float m_r = -1e30f, l_r = 0.f;
  f32x4 oacc[4] = {};

  const int srow = tid >> 2;
  const int scb = (tid & 3) * 32;
  const _Float16* Ksrc = K + (bhS + srow) * DKV + (scb >> 1);
  const _Float16* Vsrc = Vt + ((size_t)bh * DKV + srow) * SEQ + (scb >> 1);

  {
    half8 k0v = *(const half8*)(Ksrc);
    half8 k1v = *(const half8*)(Ksrc + 8);
    half8 v0v = *(const half8*)(Vsrc);
    half8 v1v = *(const half8*)(Vsrc + 8);
    char* KsW = (char*)&Ks[0][0];
    char* VsW = (char*)&Vs[0][0];
    *(half8*)(KsW + srow * 128 + swz128(srow, scb)) = k0v;
    *(half8*)(KsW + srow * 128 + swz128(srow, scb + 16)) = k1v;
    *(half8*)(VsW + srow * 128 + swz128(srow, scb)) = v0v;
    *(half8*)(VsW + srow * 128 + swz128(srow, scb + 16)) = v1v;
  }

  for (int t = 0; t < SEQ / 64; ++t) {
    __syncthreads();
    const int kt = t * 64;
    const bool pre = (t + 1 < SEQ / 64);
    half8 knA, knB, vnA, vnB;
    if (pre) {
      const _Float16* kp = Ksrc + (size_t)(kt + 64) * DKV;
      knA = *(const half8*)(kp);
      knB = *(const half8*)(kp + 8);
      const _Float16* vp = Vsrc + kt + 64;
      vnA = *(const half8*)(vp);
      vnB = *(const half8*)(vp + 8);
    }
    const char* KsB = (const char*)&Ks[t & 1][0];
    const char* VsB = (const char*)&Vs[t & 1][0];
    char* PsB = (char*)&Ps[wave][0];

    f32x4 sacc[4] = {};
    __builtin_amdgcn_s_setprio(1);
#pragma unroll
    for (int nf = 0; nf < 4; ++nf) {
      int kr = nf * 16 + l15;
      half8 kf0 = *(const half8*)(KsB + kr * 128 + swz128(kr, lg * 16));
      half8 kf1 = *(const half8*)(KsB + kr * 128 + swz128(kr, 64 + lg * 16));
      sacc[nf] = __builtin_amdgcn_mfma_f32_16x16x32_f16(kf0, qf0, sacc[nf], 0, 0, 0);
      sacc[nf] = __builtin_amdgcn_mfma_f32_16x16x32_f16(kf1, qf1, sacc[nf], 0, 0, 0);
    }
    __builtin_amdgcn_s_setprio(0);

    float sv[4][4];
    float mx = -1e30f;
#pragma unroll
    for (int nf = 0; nf < 4; ++nf) {
      f32x4 bv = *(const f32x4*)(bptr[nf] + kt);
      f32x4 mv = *(const f32x4*)(maskrow + kt + nf * 16 + lg * 4);
#pragma unroll
      for (int r = 0; r < 4; ++r) {
        float s = sacc[nf][r] + bv[r] + mv[r] * LOG2E;
        sv[nf][r] = s;
        mx = fmaxf(mx, s);
      }
    }
    mx = fmaxf(mx, __shfl_xor(mx, 16));
    mx = fmaxf(mx, __shfl_xor(mx, 32));
    const float mnew = fmaxf(m_r, mx);
    const float sc_ = __builtin_amdgcn_exp2f(m_r - mnew);
    float rs = 0.f;
#pragma unroll
    for (int nf = 0; nf < 4; ++nf) {
      half4 ph;
#pragma unroll
      for (int r = 0; r < 4; ++r) {
        float p = __builtin_amdgcn_exp2f(sv[nf][r] - mnew);
        rs += p;
        ph[r] = (_Float16)p;
      }
      *(half4*)(PsB + l15 * 144 + nf * 32 + lg * 8) = ph;
    }
    rs += __shfl_xor(rs, 16);
    rs += __shfl_xor(rs, 32);
    l_r = l_r * sc_ + rs;
    m_r = mnew;

    f32x4 scv;
#pragma unroll
    for (int r = 0; r < 4; ++r) scv[r] = __shfl(sc_, lg * 4 + r);
#pragma unroll
    for (int df = 0; df < 4; ++df) oacc[df] *= scv;

    __builtin_amdgcn_s_setprio(1);
#pragma unroll
    for (int ks = 0; ks < 2; ++ks) {
      half8 pa = *(const half8*)(PsB + l15 * 144 + ks * 64 + lg * 16);
#pragma unroll
      for (int df = 0; df < 4; ++df) {
        int vr = df * 16 + l15;
        half8 vb = *(const half8*)(VsB + vr * 128 + swz128(vr, ks * 64 + lg * 16));
        oacc[df] = __builtin_amdgcn_mfma_f32_16x16x32_f16(pa, vb, oacc[df], 0, 0, 0);
      }
    }
    __builtin_amdgcn_s_setprio(0);

    if (pre) {
      char* KsW = (char*)&Ks[(t + 1) & 1][0];
      char* VsW = (char*)&Vs[(t + 1) & 1][0];
      *(half8*)(KsW + srow * 128 + swz128(srow, scb)) = knA;
      *(half8*)(KsW + srow * 128 + swz128(srow, scb + 16)) = knB;
      *(half8*)(VsW + srow * 128 + swz128(srow, scb)) = vnA;
      *(half8*)(VsW + srow * 128 + swz128(srow, scb + 16)) = vnB;
    }
  }

  f32x4 lv;
#pragma unroll
  for (int r = 0; r < 4; ++r) lv[r] = __shfl(l_r, lg * 4 + r);
#pragma unroll
  for (int df = 0; df < 4; ++df) {
    int dd = df * 16 + l15;
#pragma unroll
    for (int r = 0; r < 4; ++r) {
      int qrow = q0 + wave * 16 + lg * 4 + r;
      AO[((size_t)(b * SEQ + qrow)) * INNER + h * DKV + dd] = (_Float16)(oacc[df][r] / lv[r]);
    }
  }
}

// ---------------- output GEMM: AO[8192,384]f16 @ WO -> out fp32, double-buffered ----------------
__global__ __launch_bounds__(256) void out_gemm(
    const _Float16* __restrict__ A, const _Float16* __restrict__ BT, float* __restrict__ C) {
  __shared__ alignas(16) _Float16 As[2][128 * 32];
  __shared__ alignas(16) _Float16 Bs[2][64 * 32];

  const int tid = threadIdx.x, lane = tid & 63, wave = tid >> 6;
  const int wm = wave >> 1, wn = wave & 1;
  const int bm = blockIdx.x, bn = blockIdx.y;
  const int l15 = lane & 15, lg = lane >> 4;

  f32x4 acc[4][2] = {};
  const int arow = tid >> 1, aseg = tid & 1;
  const int brow = tid >> 2, bchunk = tid & 3;
  const _Float16* asrc = A + (size_t)(bm * 128 + arow) * INNER + aseg * 16;
  const _Float16* bsrc = BT + (size_t)(bn * 64 + brow) * INNER + bchunk * 8;

  const int NT = INNER / 32;  // 12

  {
    half8 a0 = *(const half8*)(asrc);
    half8 a1 = *(const half8*)(asrc + 8);
    half8 b0 = *(const half8*)(bsrc);
    char* AsW = (char*)&As[0][0];
    char* BsW = (char*)&Bs[0][0];
    *(half8*)(AsW + arow * 64 + swz64(arow, aseg * 32)) = a0;
    *(half8*)(AsW + arow * 64 + swz64(arow, aseg * 32 + 16)) = a1;
    *(half8*)(BsW + brow * 64 + swz64(brow, bchunk * 16)) = b0;
  }

  for (int t = 0; t < NT; ++t) {
    __syncthreads();
    const bool pre = (t + 1 < NT);
    half8 na0, na1, nb0;
    if (pre) {
      const int kn = (t + 1) * 32;
      na0 = *(const half8*)(asrc + kn);
      na1 = *(const half8*)(asrc + kn + 8);
      nb0 = *(const half8*)(bsrc + kn);
    }

    const char* AsB = (const char*)&As[t & 1][0];
    const char* BsB = (const char*)&Bs[t & 1][0];
    half8 af[4], bf[2];
#pragma unroll
    for (int m = 0; m < 4; ++m) {
      int r = wm * 64 + m * 16 + l15;
      af[m] = *(const half8*)(AsB + r * 64 + swz64(r, lg * 16));
    }
#pragma unroll
    for (int n = 0; n < 2; ++n) {
      int r = wn * 32 + n * 16 + l15;
      bf[n] = *(const half8*)(BsB + r * 64 + swz64(r, lg * 16));
    }
    __builtin_amdgcn_s_setprio(1);
#pragma unroll
    for (int m = 0; m < 4; ++m)
#pragma unroll
      for (int n = 0; n < 2; ++n)
        acc[m][n] = __builtin_amdgcn_mfma_f32_16x16x32_f16(af[m], bf[n], acc[m][n], 0, 0, 0);
    __builtin_amdgcn_s_setprio(0);

    if (pre) {
      char* AsW = (char*)&As[(t + 1) & 1][0];
      char* BsW = (char*)&Bs[(t + 1) & 1][0];
      *(half8*)(AsW + arow * 64 + swz64(arow, aseg * 32)) = na0;
      *(half8*)(AsW + arow * 64 + swz64(arow, aseg * 32 + 16)) = na1;
      *(half8*)(BsW + brow * 64 + swz64(brow, bchunk * 16)) = nb0;
    }
  }

#pragma unroll
  for (int m = 0; m < 4; ++m)
#pragma unroll
    for (int n = 0; n < 2; ++n)
#pragma unroll
      for (int r = 0; r < 4; ++r) {
        int gm = bm * 128 + wm * 64 + m * 16 + lg * 4 + r;
        int gn = bn * 64 + wn * 32 + n * 16 + l15;
        C[(size_t)gm * DM + gn] = acc[m][n][r];
      }
}

// ---------------- launch ----------------
extern "C" void kernel_launch(void* const* d_in, const int* in_sizes, int n_in,
                              void* d_out, int out_size, void* d_ws, size_t ws_size,
                              hipStream_t stream) {
  const float* kv   = (const float*)d_in[0];
  const float* qs   = (const float*)d_in[1];
  const float* mask = (const float*)d_in[2];
  const float* WQ   = (const float*)d_in[3];
  const float* WK   = (const float*)d_in[4];
  const float* WV   = (const float*)d_in[5];
  const float* WO   = (const float*)d_in[6];
  const float* rb   = (const float*)d_in[7];
  float* out = (float*)d_out;
  char* ws = (char*)d_ws;

  const size_t WT_BYTES  = (size_t)INNER * DM * 2;
  const size_t QKV_BYTES = (size_t)BATCH * NH * SEQ * DKV * 2;
  _Float16* WqT = (_Float16*)(ws);
  _Float16* WkT = (_Float16*)(ws + WT_BYTES);
  _Float16* WvT = (_Float16*)(ws + 2 * WT_BYTES);
  _Float16* WoT = (_Float16*)(ws + 3 * WT_BYTES);
  _Float16* Qh  = (_Float16*)(ws + 4 * WT_BYTES);
  _Float16* Kh  = (_Float16*)(ws + 4 * WT_BYTES + QKV_BYTES);
  _Float16* Vth = (_Float16*)(ws + 4 * WT_BYTES + 2 * QKV_BYTES);
  _Float16* AO  = (_Float16*)(ws + 4 * WT_BYTES + 3 * QKV_BYTES);
  float* biasS  = (float*)(ws + 4 * WT_BYTES + 4 * QKV_BYTES);

  hipLaunchKernelGGL(prep_weights, dim3((4 * DM * INNER + 255) / 256), dim3(256), 0, stream,
                     WQ, WK, WV, WO, WqT, WkT, WvT, WoT);
  hipLaunchKernelGGL(prep_bias, dim3((NH * 4 * 4104 + 255) / 256), dim3(256), 0, stream, rb, biasS);
  hipLaunchKernelGGL(proj_gemm, dim3(64, 3, 3), dim3(256), 0, stream,
                     qs, kv, WqT, WkT, WvT, Qh, Kh, Vth);
  hipLaunchKernelGGL(attn_kernel, dim3(768), dim3(256), 0, stream,
                     Qh, Kh, Vth, biasS, mask, AO);
  hipLaunchKernelGGL(out_gemm, dim3(64, 23), dim3(256), 0, stream, AO, WoT, out);
}

// Round 4
// 194.635 us; speedup vs baseline: 1.7085x; 1.0776x over previous
//
#include <hip/hip_runtime.h>
#include <hip/hip_fp16.h>
#include <cstdint>

#define DM    1472
#define NH    6
#define DKV   64
#define INNER 384
#define BATCH 4
#define SEQ   2048
#define LOG2E 1.4426950408889634f

typedef __attribute__((ext_vector_type(8))) _Float16 half8;
typedef __attribute__((ext_vector_type(4))) _Float16 half4;
typedef __attribute__((ext_vector_type(4))) float f32x4;

__device__ __forceinline__ int swz64(int row, int b)  { return b ^ (((row >> 1) & 3) << 4); }
__device__ __forceinline__ int swz128(int row, int b) { return b ^ ((row & 7) << 4); }

__device__ __forceinline__ void gload16(const void* g, const void* l) {
  __builtin_amdgcn_global_load_lds((const __attribute__((address_space(1))) void*)g,
                                   (__attribute__((address_space(3))) void*)l, 16, 0, 0);
}

// ---------------- prep: weights fp32 -> fp16 transposed ----------------
__global__ void prep_weights(const float* __restrict__ WQ, const float* __restrict__ WK,
                             const float* __restrict__ WV, const float* __restrict__ WO,
                             _Float16* __restrict__ WqT, _Float16* __restrict__ WkT,
                             _Float16* __restrict__ WvT, _Float16* __restrict__ WoT) {
  int idx = blockIdx.x * blockDim.x + threadIdx.x;
  const int per = DM * INNER;
  if (idx >= 4 * per) return;
  int which = idx / per;
  int i = idx - which * per;
  if (which < 3) {
    const float* W = which == 0 ? WQ : (which == 1 ? WK : WV);
    _Float16* T = which == 0 ? WqT : (which == 1 ? WkT : WvT);
    int k = i / INNER, n = i - (i / INNER) * INNER;
    T[(size_t)n * DM + k] = (_Float16)W[i];   // [INNER][DM] = W^T
  } else {
    int k = i / DM, n = i - (i / DM) * DM;
    WoT[(size_t)n * INNER + k] = (_Float16)WO[i];  // [DM][INNER] = WO^T
  }
}

// ---------------- prep: shift-replicated bias table biasS[h][c][4104] ----------------
__global__ void prep_bias(const float* __restrict__ rel_bias, float* __restrict__ biasS) {
  int idx = blockIdx.x * blockDim.x + threadIdx.x;
  const int TOT = NH * 4 * 4104;
  if (idx >= TOT) return;
  int h = idx / (4 * 4104);
  int rem = idx - h * 4 * 4104;
  int cc = rem / 4104;
  int i = rem - cc * 4104;
  int j = i + cc; if (j > 4094) j = 4094;
  int d = j - 2047;                 // relative position k - q
  int ret = d > 0 ? 16 : 0;
  int a = d < 0 ? -d : d;
  int bucket;
  if (a < 8) bucket = ret + a;
  else {
    int large;
    if      (a >= 91) large = 15;
    else if (a >= 64) large = 14;
    else if (a >= 46) large = 13;
    else if (a >= 32) large = 12;
    else if (a >= 23) large = 11;
    else if (a >= 16) large = 10;
    else if (a >= 12) large = 9;
    else              large = 8;
    bucket = ret + large;
  }
  biasS[idx] = rel_bias[bucket * NH + h] * LOG2E;
}

// ---------------- projection GEMM, m97-structure ----------------
// 128x128x32 tiles, global_load_lds staging (A fp32 raw, B fp16), dbuf, 1 barrier/iter.
// by 0..2: Q = Xq @ WqT rows (scaled LOG2E); by 3..8: KV = Xkv @ [WkT;WvT] rows.
__global__ __launch_bounds__(256) void proj_gemm(
    const float* __restrict__ Xq, const float* __restrict__ Xkv,
    const _Float16* __restrict__ WqT, const _Float16* __restrict__ WkvT,
    _Float16* __restrict__ Qo, _Float16* __restrict__ Ko, _Float16* __restrict__ Vto) {
  const int bm = blockIdx.x, by = blockIdx.y;
  const bool isQ = by < 3;
  const float* __restrict__ X = isQ ? Xq : Xkv;
  const _Float16* __restrict__ WT = isQ ? (WqT + (size_t)by * 128 * DM)
                                        : (WkvT + (size_t)(by - 3) * 128 * DM);

  __shared__ alignas(16) float    As[2][128 * 32];   // fp32 A, 16KB per buf
  __shared__ alignas(16) _Float16 Bs[2][128 * 32];   // fp16 B,  8KB per buf

  const int tid = threadIdx.x;
  const int lane = tid & 63, wave = tid >> 6;
  const int wm = wave >> 1, wn = wave & 1;
  const int l15 = lane & 15, lg = lane >> 4;

  f32x4 acc[4][4] = {};

  // ---- staging geometry (pre-swizzled global source, linear LDS dest) ----
  // A: 16KB/tile = 16 wave-calls of 1KB; this wave does calls waveA+0..3.
  //    call c: rows (wave*4+c)*8 + (lane>>3), source col floats: t*32 + 4*((lane&7)^(lane>>3))
  const int aoff = 4 * ((lane & 7) ^ (lane >> 3));
  const float* asrc[4];
#pragma unroll
  for (int c = 0; c < 4; ++c)
    asrc[c] = X + (size_t)(bm * 128 + (wave * 4 + c) * 8 + (lane >> 3)) * DM + aoff;
  // B: 8KB/tile = 8 wave-calls; this wave does calls wave*2+0..1.
  //    call c: rows (wave*2+c)*16 + (lane>>2), source col halfs: t*32 + 8*((lane&3)^((lane>>3)&3))
  const int boff = 8 * ((lane & 3) ^ ((lane >> 3) & 3));
  const _Float16* bsrc[2];
#pragma unroll
  for (int c = 0; c < 2; ++c)
    bsrc[c] = WT + (size_t)((wave * 2 + c) * 16 + (lane >> 2)) * DM + boff;

  const int NT = DM / 32;   // 46

  // prologue: stage tile 0 into buf 0
#pragma unroll
  for (int c = 0; c < 4; ++c)
    gload16(asrc[c], (const char*)&As[0][0] + (wave * 4 + c) * 1024);
#pragma unroll
  for (int c = 0; c < 2; ++c)
    gload16(bsrc[c], (const char*)&Bs[0][0] + (wave * 2 + c) * 1024);
  __syncthreads();

  for (int t = 0; t < NT; ++t) {
    // issue prefetch of tile t+1 into the other buffer (stays in flight through MFMA)
    if (t + 1 < NT) {
      const int nb = (t + 1) & 1;
      const int kf = (t + 1) * 32;
#pragma unroll
      for (int c = 0; c < 4; ++c)
        gload16(asrc[c] + kf, (const char*)&As[nb][0] + (wave * 4 + c) * 1024);
#pragma unroll
      for (int c = 0; c < 2; ++c)
        gload16(bsrc[c] + kf, (const char*)&Bs[nb][0] + (wave * 2 + c) * 1024);
    }

    const char* Ab = (const char*)&As[t & 1][0];
    const char* Bb = (const char*)&Bs[t & 1][0];
    half8 af[4], bf[4];
#pragma unroll
    for (int m = 0; m < 4; ++m) {
      int r = wm * 64 + m * 16 + l15;
      int s = (r & 7) << 4;
      f32x4 x0 = *(const f32x4*)(Ab + r * 128 + ((lg * 32) ^ s));
      f32x4 x1 = *(const f32x4*)(Ab + r * 128 + ((lg * 32 + 16) ^ s));
      half8 h;
#pragma unroll
      for (int j = 0; j < 4; ++j) { h[j] = (_Float16)x0[j]; h[4 + j] = (_Float16)x1[j]; }
      af[m] = h;
    }
#pragma unroll
    for (int n = 0; n < 4; ++n) {
      int r = wn * 64 + n * 16 + l15;
      bf[n] = *(const half8*)(Bb + r * 64 + ((lg * 16) ^ (((r >> 1) & 3) << 4)));
    }

    __builtin_amdgcn_s_setprio(1);
#pragma unroll
    for (int m = 0; m < 4; ++m)
#pragma unroll
      for (int n = 0; n < 4; ++n)
        acc[m][n] = __builtin_amdgcn_mfma_f32_16x16x32_f16(af[m], bf[n], acc[m][n], 0, 0, 0);
    __builtin_amdgcn_s_setprio(0);

    __syncthreads();   // drains vmcnt (prefetch complete) + protects LDS reuse
  }

  // epilogue: route to Q / K / V^T
#pragma unroll
  for (int m = 0; m < 4; ++m)
#pragma unroll
    for (int n = 0; n < 4; ++n)
#pragma unroll
      for (int r = 0; r < 4; ++r) {
        int gm = bm * 128 + wm * 64 + m * 16 + lg * 4 + r;
        int gnl = wn * 64 + n * 16 + l15;
        int b = gm >> 11, s = gm & 2047;
        float av = acc[m][n][r];
        if (isQ) {
          int gn = by * 128 + gnl;
          int h = gn >> 6, dd = gn & 63;
          Qo[((size_t)(b * NH + h) * SEQ + s) * DKV + dd] = (_Float16)(av * LOG2E);
        } else {
          int gn = (by - 3) * 128 + gnl;
          if (gn < INNER) {
            int h = gn >> 6, dd = gn & 63;
            Ko[((size_t)(b * NH + h) * SEQ + s) * DKV + dd] = (_Float16)av;
          } else {
            int gnv = gn - INNER;
            int h = gnv >> 6, dd = gnv & 63;
            Vto[((size_t)(b * NH + h) * DKV + dd) * SEQ + s] = (_Float16)av;
          }
        }
      }
}

// ---------------- flash attention, swapped QK^T: S^T[k][q] per lane ----------------
__global__ __launch_bounds__(256) void attn_kernel(
    const _Float16* __restrict__ Q, const _Float16* __restrict__ K, const _Float16* __restrict__ Vt,
    const float* __restrict__ biasS, const float* __restrict__ mask, _Float16* __restrict__ AO) {
  const int bid = blockIdx.x;
  const int g = (bid & 7) * 96 + (bid >> 3);
  const int bh = g >> 5, qb = g & 31;
  const int b = bh / NH, h = bh - b * NH;
  const int q0 = qb * 64;
  const int tid = threadIdx.x, lane = tid & 63, wave = tid >> 6;
  const int l15 = lane & 15, lg = lane >> 4;

  __shared__ alignas(16) _Float16 Ks[2][64 * 64];
  __shared__ alignas(16) _Float16 Vs[2][64 * 64];
  __shared__ alignas(16) _Float16 Ps[4][16 * 72];   // 144B rows (pad) per wave

  const size_t bhS = (size_t)bh * SEQ;
  const int qq = q0 + wave * 16 + l15;

  const _Float16* Qbase = Q + (bhS + q0 + wave * 16) * DKV;
  half8 qf0 = *(const half8*)(Qbase + (size_t)l15 * DKV + lg * 8);
  half8 qf1 = *(const half8*)(Qbase + (size_t)l15 * DKV + 32 + lg * 8);

  const float* maskrow = mask + (size_t)b * SEQ * SEQ + (size_t)qq * SEQ;
  const int c = (3 - l15) & 3;
  const float* bptr[4];
#pragma unroll
  for (int nf = 0; nf < 4; ++nf)
    bptr[nf] = biasS + (size_t)(h * 4 + c) * 4104 + (nf * 16 + lg * 4 - qq + 2047 - c);

  float m_r = -1e30f, l_r = 0.f;
  f32x4 oacc[4] = {};

  const int srow = tid >> 2;
  const int scb = (tid & 3) * 32;
  const _Float16* Ksrc = K + (bhS + srow) * DKV + (scb >> 1);
  const _Float16* Vsrc = Vt + ((size_t)bh * DKV + srow) * SEQ + (scb >> 1);

  {
    half8 k0v = *(const half8*)(Ksrc);
    half8 k1v = *(const half8*)(Ksrc + 8);
    half8 v0v = *(const half8*)(Vsrc);
    half8 v1v = *(const half8*)(Vsrc + 8);
    char* KsW = (char*)&Ks[0][0];
    char* VsW = (char*)&Vs[0][0];
    *(half8*)(KsW + srow * 128 + swz128(srow, scb)) = k0v;
    *(half8*)(KsW + srow * 128 + swz128(srow, scb + 16)) = k1v;
    *(half8*)(VsW + srow * 128 + swz128(srow, scb)) = v0v;
    *(half8*)(VsW + srow * 128 + swz128(srow, scb + 16)) = v1v;
  }

  for (int t = 0; t < SEQ / 64; ++t) {
    __syncthreads();
    const int kt = t * 64;
    const bool pre = (t + 1 < SEQ / 64);
    half8 knA, knB, vnA, vnB;
    if (pre) {
      const _Float16* kp = Ksrc + (size_t)(kt + 64) * DKV;
      knA = *(const half8*)(kp);
      knB = *(const half8*)(kp + 8);
      const _Float16* vp = Vsrc + kt + 64;
      vnA = *(const half8*)(vp);
      vnB = *(const half8*)(vp + 8);
    }
    const char* KsB = (const char*)&Ks[t & 1][0];
    const char* VsB = (const char*)&Vs[t & 1][0];
    char* PsB = (char*)&Ps[wave][0];

    f32x4 sacc[4] = {};
    __builtin_amdgcn_s_setprio(1);
#pragma unroll
    for (int nf = 0; nf < 4; ++nf) {
      int kr = nf * 16 + l15;
      half8 kf0 = *(const half8*)(KsB + kr * 128 + swz128(kr, lg * 16));
      half8 kf1 = *(const half8*)(KsB + kr * 128 + swz128(kr, 64 + lg * 16));
      sacc[nf] = __builtin_amdgcn_mfma_f32_16x16x32_f16(kf0, qf0, sacc[nf], 0, 0, 0);
      sacc[nf] = __builtin_amdgcn_mfma_f32_16x16x32_f16(kf1, qf1, sacc[nf], 0, 0, 0);
    }
    __builtin_amdgcn_s_setprio(0);

    float sv[4][4];
    float mx = -1e30f;
#pragma unroll
    for (int nf = 0; nf < 4; ++nf) {
      f32x4 bv = *(const f32x4*)(bptr[nf] + kt);
      f32x4 mv = *(const f32x4*)(maskrow + kt + nf * 16 + lg * 4);
#pragma unroll
      for (int r = 0; r < 4; ++r) {
        float s = sacc[nf][r] + bv[r] + mv[r] * LOG2E;
        sv[nf][r] = s;
        mx = fmaxf(mx, s);
      }
    }
    mx = fmaxf(mx, __shfl_xor(mx, 16));
    mx = fmaxf(mx, __shfl_xor(mx, 32));
    const float mnew = fmaxf(m_r, mx);
    const float sc_ = __builtin_amdgcn_exp2f(m_r - mnew);
    float rs = 0.f;
#pragma unroll
    for (int nf = 0; nf < 4; ++nf) {
      half4 ph;
#pragma unroll
      for (int r = 0; r < 4; ++r) {
        float p = __builtin_amdgcn_exp2f(sv[nf][r] - mnew);
        rs += p;
        ph[r] = (_Float16)p;
      }
      *(half4*)(PsB + l15 * 144 + nf * 32 + lg * 8) = ph;
    }
    rs += __shfl_xor(rs, 16);
    rs += __shfl_xor(rs, 32);
    l_r = l_r * sc_ + rs;
    m_r = mnew;

    f32x4 scv;
#pragma unroll
    for (int r = 0; r < 4; ++r) scv[r] = __shfl(sc_, lg * 4 + r);
#pragma unroll
    for (int df = 0; df < 4; ++df) oacc[df] *= scv;

    __builtin_amdgcn_s_setprio(1);
#pragma unroll
    for (int ks = 0; ks < 2; ++ks) {
      half8 pa = *(const half8*)(PsB + l15 * 144 + ks * 64 + lg * 16);
#pragma unroll
      for (int df = 0; df < 4; ++df) {
        int vr = df * 16 + l15;
        half8 vb = *(const half8*)(VsB + vr * 128 + swz128(vr, ks * 64 + lg * 16));
        oacc[df] = __builtin_amdgcn_mfma_f32_16x16x32_f16(pa, vb, oacc[df], 0, 0, 0);
      }
    }
    __builtin_amdgcn_s_setprio(0);

    if (pre) {
      char* KsW = (char*)&Ks[(t + 1) & 1][0];
      char* VsW = (char*)&Vs[(t + 1) & 1][0];
      *(half8*)(KsW + srow * 128 + swz128(srow, scb)) = knA;
      *(half8*)(KsW + srow * 128 + swz128(srow, scb + 16)) = knB;
      *(half8*)(VsW + srow * 128 + swz128(srow, scb)) = vnA;
      *(half8*)(VsW + srow * 128 + swz128(srow, scb + 16)) = vnB;
    }
  }

  f32x4 lv;
#pragma unroll
  for (int r = 0; r < 4; ++r) lv[r] = __shfl(l_r, lg * 4 + r);
#pragma unroll
  for (int df = 0; df < 4; ++df) {
    int dd = df * 16 + l15;
#pragma unroll
    for (int r = 0; r < 4; ++r) {
      int qrow = q0 + wave * 16 + lg * 4 + r;
      AO[((size_t)(b * SEQ + qrow)) * INNER + h * DKV + dd] = (_Float16)(oacc[df][r] / lv[r]);
    }
  }
}

// ---------------- output GEMM: AO[8192,384]f16 @ WO -> out fp32, double-buffered ----------------
__global__ __launch_bounds__(256) void out_gemm(
    const _Float16* __restrict__ A, const _Float16* __restrict__ BT, float* __restrict__ C) {
  __shared__ alignas(16) _Float16 As[2][128 * 32];
  __shared__ alignas(16) _Float16 Bs[2][64 * 32];

  const int tid = threadIdx.x, lane = tid & 63, wave = tid >> 6;
  const int wm = wave >> 1, wn = wave & 1;
  const int bm = blockIdx.x, bn = blockIdx.y;
  const int l15 = lane & 15, lg = lane >> 4;

  f32x4 acc[4][2] = {};
  const int arow = tid >> 1, aseg = tid & 1;
  const int brow = tid >> 2, bchunk = tid & 3;
  const _Float16* asrc = A + (size_t)(bm * 128 + arow) * INNER + aseg * 16;
  const _Float16* bsrc = BT + (size_t)(bn * 64 + brow) * INNER + bchunk * 8;

  const int NT = INNER / 32;  // 12

  {
    half8 a0 = *(const half8*)(asrc);
    half8 a1 = *(const half8*)(asrc + 8);
    half8 b0 = *(const half8*)(bsrc);
    char* AsW = (char*)&As[0][0];
    char* BsW = (char*)&Bs[0][0];
    *(half8*)(AsW + arow * 64 + swz64(arow, aseg * 32)) = a0;
    *(half8*)(AsW + arow * 64 + swz64(arow, aseg * 32 + 16)) = a1;
    *(half8*)(BsW + brow * 64 + swz64(brow, bchunk * 16)) = b0;
  }

  for (int t = 0; t < NT; ++t) {
    __syncthreads();
    const bool pre = (t + 1 < NT);
    half8 na0, na1, nb0;
    if (pre) {
      const int kn = (t + 1) * 32;
      na0 = *(const half8*)(asrc + kn);
      na1 = *(const half8*)(asrc + kn + 8);
      nb0 = *(const half8*)(bsrc + kn);
    }

    const char* AsB = (const char*)&As[t & 1][0];
    const char* BsB = (const char*)&Bs[t & 1][0];
    half8 af[4], bf[2];
#pragma unroll
    for (int m = 0; m < 4; ++m) {
      int r = wm * 64 + m * 16 + l15;
      af[m] = *(const half8*)(AsB + r * 64 + swz64(r, lg * 16));
    }
#pragma unroll
    for (int n = 0; n < 2; ++n) {
      int r = wn * 32 + n * 16 + l15;
      bf[n] = *(const half8*)(BsB + r * 64 + swz64(r, lg * 16));
    }
    __builtin_amdgcn_s_setprio(1);
#pragma unroll
    for (int m = 0; m < 4; ++m)
#pragma unroll
      for (int n = 0; n < 2; ++n)
        acc[m][n] = __builtin_amdgcn_mfma_f32_16x16x32_f16(af[m], bf[n], acc[m][n], 0, 0, 0);
    __builtin_amdgcn_s_setprio(0);

    if (pre) {
      char* AsW = (char*)&As[(t + 1) & 1][0];
      char* BsW = (char*)&Bs[(t + 1) & 1][0];
      *(half8*)(AsW + arow * 64 + swz64(arow, aseg * 32)) = na0;
      *(half8*)(AsW + arow * 64 + swz64(arow, aseg * 32 + 16)) = na1;
      *(half8*)(BsW + brow * 64 + swz64(brow, bchunk * 16)) = nb0;
    }
  }

#pragma unroll
  for (int m = 0; m < 4; ++m)
#pragma unroll
    for (int n = 0; n < 2; ++n)
#pragma unroll
      for (int r = 0; r < 4; ++r) {
        int gm = bm * 128 + wm * 64 + m * 16 + lg * 4 + r;
        int gn = bn * 64 + wn * 32 + n * 16 + l15;
        C[(size_t)gm * DM + gn] = acc[m][n][r];
      }
}

// ---------------- launch ----------------
extern "C" void kernel_launch(void* const* d_in, const int* in_sizes, int n_in,
                              void* d_out, int out_size, void* d_ws, size_t ws_size,
                              hipStream_t stream) {
  const float* kv   = (const float*)d_in[0];
  const float* qs   = (const float*)d_in[1];
  const float* mask = (const float*)d_in[2];
  const float* WQ   = (const float*)d_in[3];
  const float* WK   = (const float*)d_in[4];
  const float* WV   = (const float*)d_in[5];
  const float* WO   = (const float*)d_in[6];
  const float* rb   = (const float*)d_in[7];
  float* out = (float*)d_out;
  char* ws = (char*)d_ws;

  const size_t WT_BYTES  = (size_t)INNER * DM * 2;
  const size_t QKV_BYTES = (size_t)BATCH * NH * SEQ * DKV * 2;
  _Float16* WqT = (_Float16*)(ws);
  _Float16* WkT = (_Float16*)(ws + WT_BYTES);      // WkT + WvT contiguous => [768][DM]
  _Float16* WvT = (_Float16*)(ws + 2 * WT_BYTES);
  _Float16* WoT = (_Float16*)(ws + 3 * WT_BYTES);
  _Float16* Qh  = (_Float16*)(ws + 4 * WT_BYTES);
  _Float16* Kh  = (_Float16*)(ws + 4 * WT_BYTES + QKV_BYTES);
  _Float16* Vth = (_Float16*)(ws + 4 * WT_BYTES + 2 * QKV_BYTES);
  _Float16* AO  = (_Float16*)(ws + 4 * WT_BYTES + 3 * QKV_BYTES);
  float* biasS  = (float*)(ws + 4 * WT_BYTES + 4 * QKV_BYTES);

  hipLaunchKernelGGL(prep_weights, dim3((4 * DM * INNER + 255) / 256), dim3(256), 0, stream,
                     WQ, WK, WV, WO, WqT, WkT, WvT, WoT);
  hipLaunchKernelGGL(prep_bias, dim3((NH * 4 * 4104 + 255) / 256), dim3(256), 0, stream, rb, biasS);
  hipLaunchKernelGGL(proj_gemm, dim3(64, 9), dim3(256), 0, stream,
                     qs, kv, WqT, WkT, Qh, Kh, Vth);
  hipLaunchKernelGGL(attn_kernel, dim3(768), dim3(256), 0, stream,
                     Qh, Kh, Vth, biasS, mask, AO);
  hipLaunchKernelGGL(out_gemm, dim3(64, 23), dim3(256), 0, stream, AO, WoT, out);
}